// Round 8
// baseline (596.209 us; speedup 1.0000x reference)
//
#include <hip/hip_runtime.h>
#include <hip/hip_bf16.h>
#include <stdint.h>

// Transformer block: B=8, T=2048, C=1024, fp32 in/out, bf16 MFMA internally.
// Round 8: m201-faithful 4-phase K-tile schedule:
//   phase = { ds_read (4 or 8, in-phase operand) | stage 1 half-tile (t+2)
//             | s_barrier | lgkmcnt(0) | setprio(1) 16 MFMA setprio(0)
//             | [P3: counted vmcnt] | s_barrier }
//   ONE vmcnt(4) per K-tile (ledger-verified: forces exactly tile t+1's
//   8 loads, 3-5 phases after issue; 4 loads always in flight, never drain).
// T1 XCD remap, T2 LDS XOR swizzle, epilogues, launcher unchanged.

#define C_DIM 1024
#define T_DIM 2048
#define B_DIM 8

typedef float f32x4 __attribute__((ext_vector_type(4)));
typedef __bf16 bf16x8 __attribute__((ext_vector_type(8)));

typedef const __attribute__((address_space(1))) void gvoid_t;
typedef __attribute__((address_space(3))) void lvoid_t;

__device__ __forceinline__ void gload_lds16(const void* g, void* l) {
    __builtin_amdgcn_global_load_lds((gvoid_t*)g, (lvoid_t*)l, 16, 0, 0);
}

__device__ __forceinline__ unsigned short f2bf_bits(float f) {
    __hip_bfloat16 h = __float2bfloat16(f);
    return *reinterpret_cast<unsigned short*>(&h);
}

// Bijective XCD-chunked remap (m204)
__device__ __forceinline__ void xcd_remap(int& bx, int& by, int& bz) {
    const int gx = gridDim.x, gy = gridDim.y;
    const int nwg = gx * gy * (int)gridDim.z;
    const int orig = bx + gx * (by + gy * bz);
    const int q = nwg >> 3, r = nwg & 7;
    const int xcd = orig & 7, pos = orig >> 3;
    const int neu = (xcd < r ? xcd * (q + 1) : r * (q + 1) + (xcd - r) * q) + pos;
    bx = neu % gx;
    const int t = neu / gx;
    by = t % gy;
    bz = t / gy;
}

#define BAR() do { __builtin_amdgcn_s_barrier(); __builtin_amdgcn_sched_barrier(0); } while(0)
#define VMCNT(n) do { asm volatile("s_waitcnt vmcnt(" #n ")" ::: "memory"); \
                      __builtin_amdgcn_sched_barrier(0); } while(0)
#define LGKM0() do { asm volatile("s_waitcnt lgkmcnt(0)" ::: "memory"); \
                     __builtin_amdgcn_sched_barrier(0); } while(0)

// ds-read A fragments (4 mf x 2 ks), wave-row-half hq (0=rows wr*128..+63), buf
#define RD_A(dst, buf, hq) do { \
    _Pragma("unroll") \
    for (int mf_ = 0; mf_ < 4; ++mf_) { \
        const char* p_ = lds + (buf)*32768 + wrb + (hq)*8192 + mf_*2048; \
        dst[mf_][0] = *(const bf16x8*)(p_ + offk0); \
        dst[mf_][1] = *(const bf16x8*)(p_ + offk1); \
    } \
} while(0)

// ds-read B fragments (2 n2 x 2 ks), wave-col-half nh, buf
#define RD_B(dst, buf, nh) do { \
    _Pragma("unroll") \
    for (int n2_ = 0; n2_ < 2; ++n2_) { \
        const char* p_ = lds + 65536 + (buf)*32768 + wcb + ((nh)*2 + n2_)*2048; \
        dst[n2_][0] = *(const bf16x8*)(p_ + offk0); \
        dst[n2_][1] = *(const bf16x8*)(p_ + offk1); \
    } \
} while(0)

// 16 MFMA for quadrant (Mh,Nh) from reg sets aS/bS
#define MMQ(aS, bS, Mh, Nh) do { \
    __builtin_amdgcn_s_setprio(1); \
    _Pragma("unroll") \
    for (int m4_ = 0; m4_ < 4; ++m4_) \
    _Pragma("unroll") \
    for (int n2_ = 0; n2_ < 2; ++n2_) \
    _Pragma("unroll") \
    for (int ks_ = 0; ks_ < 2; ++ks_) \
        acc[(Mh)*4 + m4_][(Nh)*2 + n2_] = __builtin_amdgcn_mfma_f32_16x16x32_bf16( \
            aS[m4_][ks_], bS[n2_][ks_], acc[(Mh)*4 + m4_][(Nh)*2 + n2_], 0, 0, 0); \
    __builtin_amdgcn_s_setprio(0); \
} while(0)

// stage one 16KB half-tile (2 x gload_lds16 per thread)
#define STA(buf, half, kt) do { \
    const int go_ = aoff + (half)*128*lda + (kt)*64; \
    char* lp_ = ldsw + (buf)*32768 + (half)*16384; \
    gload_lds16(A + go_,            lp_); \
    gload_lds16(A + go_ + 64*lda,   lp_ + 8192); \
} while(0)
#define STB(buf, half, kt) do { \
    const int go_ = boff + (half)*128*ldb + (kt)*64; \
    char* lp_ = ldsw + 65536 + (buf)*32768 + (half)*16384; \
    gload_lds16(Bt + go_,           lp_); \
    gload_lds16(Bt + go_ + 64*ldb,  lp_ + 8192); \
} while(0)

// ---------------------------------------------------------------------------
// One K-tile: 4 phases. Reads (in-phase, covered by LGKM0 before MFMA):
//   P1: bL(t)  -> MM(aX,bL)(Mh0,N0)     [aX(t) read at (t-1).P4]
//   P2: bH(t)  -> MM(aX,bH)(Mh0,N1)   | stage Blo(t+2)
//   P3: aY(t)  -> MM(aY,bH)(Mh1,N1)   | stage Bhi(t+2) | VMCNT(4|0)
//   P4: aX(t+1)-> MM(aY,bL)(Mh1,N0)   | stage Alo+Ahi(t+2)
// FIFO ledger (2 loads/half): at t.P3-end outstanding =
//   {Alo,Ahi}(t+1)[(t-1).P4] + Blo(t+2)[t.P2] + Bhi(t+2)[t.P3] = 8;
//   VMCNT(4) forces tile t+1's A halves (B halves forced at (t-1).P3);
//   all of t+1 landed before its first read at t.P4-top.  WAR: each region
//   staged >=1 phase after its last ds_read phase (lgkm0+barrier ordered).
// ---------------------------------------------------------------------------
#define TILE_BODY(t, STG) do { \
    const int buf_ = (t) & 1; \
    /* P1 */ \
    RD_B(bL, buf_, 0); \
    BAR(); LGKM0(); MMQ(aX, bL, 0, 0); BAR(); \
    /* P2 */ \
    if (STG) STB(buf_, 0, (t) + 2); \
    RD_B(bH, buf_, 1); \
    BAR(); LGKM0(); MMQ(aX, bH, 0, 1); BAR(); \
    /* P3 */ \
    if (STG) STB(buf_, 1, (t) + 2); \
    RD_A(aY, buf_, 1); \
    BAR(); LGKM0(); MMQ(aY, bH, 1, 1); \
    if (STG) { VMCNT(4); } else { VMCNT(0); } \
    BAR(); \
    /* P4 */ \
    if (STG) { STA(buf_, 0, (t) + 2); STA(buf_, 1, (t) + 2); } \
    if ((t) + 1 < NT) RD_A(aX, buf_ ^ 1, 0); \
    BAR(); LGKM0(); MMQ(aY, bL, 1, 0); BAR(); \
} while(0)

// ---------------------------------------------------------------------------
// 256x256 GEMM: C[M,N] = A[M,K] x Bt[N,K], bf16 in. BK=64, 8 waves (2Mx4N).
// EPI: 0 bf16; 2 fp32 + residual R (Cout may alias R); 3 bf16 silu;
//      4 bf16*scale; 6 fused qkv route (Cout=q, C2=k, C3=vT[B][C][T]).
// CMODE: 0 none; 1 causal block skip; 2 causal K clip (kmax = m0+256).
// ---------------------------------------------------------------------------
template<int EPI, int CMODE>
__global__ __launch_bounds__(512, 2)
void gemm256(const __hip_bfloat16* A, const __hip_bfloat16* Bt,
             void* Cout, const float* R, void* C2, void* C3,
             int K, int lda, int ldb, int ldc,
             long long sA, long long sB, long long sC, float scale)
{
    int bx = blockIdx.x, by = blockIdx.y, bz = blockIdx.z;
    xcd_remap(bx, by, bz);
    if constexpr (CMODE == 1) { if (bx > by) return; }

    const int tid  = threadIdx.x;
    const int lane = tid & 63, wave = tid >> 6;
    const int l15  = lane & 15, l4 = lane >> 4;
    const int wr   = wave >> 2, wc = wave & 3;      // 2 x 4 wave grid
    const int m0   = by * 256, n0 = bx * 256;
    const int z    = bz;

    A  += (long long)z * sA;
    Bt += (long long)z * sB;

    __shared__ __align__(16) char lds_[131072];     // A [0,64K), B [64K,128K)
    char* lds  = lds_;
    char* ldsw = lds_ + wave * 1024;

    int kmax = K;
    if constexpr (CMODE == 2) { int km = m0 + 256; kmax = km < K ? km : K; }
    const int NT = kmax >> 6;                       // NT >= 4 for all shapes

    // read-side lane offsets: row-local byte = l15*128 + ((ks*4+l4)^(l15&7))*16
    const int offk0 = l15 * 128 + (((l4)     ^ (l15 & 7)) << 4);
    const int offk1 = l15 * 128 + (((4 + l4) ^ (l15 & 7)) << 4);
    const int wrb = wr * 16384, wcb = wc * 8192;

    // staging: thread -> (row = tid>>3, slot = (tid&7)^(row&7)); inverse swizzle on src
    const int rowq  = tid >> 3;
    const int sslot = (tid & 7) ^ (rowq & 7);
    const int aoff  = (m0 + rowq) * lda + sslot * 8;
    const int boff  = (n0 + rowq) * ldb + sslot * 8;

    f32x4 acc[8][4];
#pragma unroll
    for (int i = 0; i < 8; ++i)
#pragma unroll
        for (int j = 0; j < 4; ++j) acc[i][j] = (f32x4){0.f, 0.f, 0.f, 0.f};
    bf16x8 aX[4][2], aY[4][2], bL[2][2], bH[2][2];

    // prologue: stage tiles 0,1 fully; force tile0 (leave tile1's 8 flying);
    // read aX(0) (tile0's P4-equivalent read).
    STB(0, 0, 0); STB(0, 1, 0); STA(0, 0, 0); STA(0, 1, 0);
    STB(1, 0, 1); STB(1, 1, 1); STA(1, 0, 1); STA(1, 1, 1);
    VMCNT(8);
    BAR();
    RD_A(aX, 0, 0);

    int t = 0;
    for (; t < NT - 2; ++t) TILE_BODY(t, true);
    for (; t < NT; ++t)     TILE_BODY(t, false);

    asm volatile("s_waitcnt vmcnt(0)" ::: "memory");

    // epilogue: row = m0 + wr*128 + mf*16 + l4*4 + r ; col = n0 + wc*64 + nf*16 + l15
    const long long cbase = (long long)z * sC;
#pragma unroll
    for (int mf = 0; mf < 8; ++mf) {
        const int rbase = m0 + wr * 128 + mf * 16 + l4 * 4;
#pragma unroll
        for (int nf = 0; nf < 4; ++nf) {
            const int col = n0 + wc * 64 + nf * 16 + l15;
#pragma unroll
            for (int r = 0; r < 4; ++r) {
                const float v = acc[mf][nf][r];
                const int row = rbase + r;
                if constexpr (EPI == 6) {
                    const int seg = col >> 10, ncol = col & 1023;
                    if (seg == 0) {
                        ((__hip_bfloat16*)Cout)[(long long)row * 1024 + ncol] =
                            __float2bfloat16(v);
                    } else if (seg == 1) {
                        ((__hip_bfloat16*)C2)[(long long)row * 1024 + ncol] =
                            __float2bfloat16(v);
                    } else {
                        const int b = row >> 11, tt = row & 2047;
                        ((__hip_bfloat16*)C3)[((long long)b * C_DIM + ncol) * T_DIM + tt] =
                            __float2bfloat16(v);
                    }
                } else {
                    const long long idx = cbase + (long long)row * ldc + col;
                    if constexpr (EPI == 0) {
                        ((__hip_bfloat16*)Cout)[idx] = __float2bfloat16(v);
                    } else if constexpr (EPI == 2) {
                        ((float*)Cout)[idx] = v + R[idx];
                    } else if constexpr (EPI == 3) {
                        const float s = v / (1.f + __expf(-v));
                        ((__hip_bfloat16*)Cout)[idx] = __float2bfloat16(s);
                    } else { // EPI == 4
                        ((__hip_bfloat16*)Cout)[idx] = __float2bfloat16(v * scale);
                    }
                }
            }
        }
    }
}

// ---------------------------------------------------------------------------
// RMSNorm: one block per row of C_DIM, fp32 in -> bf16 out
// ---------------------------------------------------------------------------
__global__ __launch_bounds__(256)
void rmsnorm_kernel(const float* __restrict__ x, const float* __restrict__ g,
                    __hip_bfloat16* __restrict__ out)
{
    const long long row = blockIdx.x;
    const int tid = threadIdx.x;
    const float4 v = ((const float4*)(x + row * C_DIM))[tid];
    float ss = v.x * v.x + v.y * v.y + v.z * v.z + v.w * v.w;
#pragma unroll
    for (int off = 32; off; off >>= 1) ss += __shfl_xor(ss, off);
    __shared__ float red[4];
    if ((tid & 63) == 0) red[tid >> 6] = ss;
    __syncthreads();
    ss = red[0] + red[1] + red[2] + red[3];
    const float sc = rsqrtf(ss * (1.0f / C_DIM) + 1e-6f);
    const float4 gv = ((const float4*)g)[tid];
    ushort4 u;
    u.x = f2bf_bits(v.x * sc * gv.x);
    u.y = f2bf_bits(v.y * sc * gv.y);
    u.z = f2bf_bits(v.z * sc * gv.z);
    u.w = f2bf_bits(v.w * sc * gv.w);
    *(ushort4*)(out + row * C_DIM + tid * 4) = u;
}

// ---------------------------------------------------------------------------
// Causal softmax, IN PLACE on bf16 S [B,T,T] -> P bf16 (zeros above diagonal).
// ---------------------------------------------------------------------------
__global__ __launch_bounds__(256)
void softmax_causal(__hip_bfloat16* __restrict__ SP)
{
    const int i = blockIdx.x, b = blockIdx.y;
    __hip_bfloat16* row = SP + ((long long)b * T_DIM + i) * T_DIM;
    const int tid = threadIdx.x;
    const int jbase = tid * 8;

    uint4 raw = ((const uint4*)row)[tid];
    float v[8];
    const unsigned w[4] = {raw.x, raw.y, raw.z, raw.w};
#pragma unroll
    for (int c = 0; c < 4; ++c) {
        unsigned lo = w[c] << 16;
        unsigned hi = w[c] & 0xFFFF0000u;
        v[2 * c]     = __uint_as_float(lo);
        v[2 * c + 1] = __uint_as_float(hi);
    }
#pragma unroll
    for (int e = 0; e < 8; ++e)
        if (jbase + e > i) v[e] = -1e30f;

    float m = v[0];
#pragma unroll
    for (int e = 1; e < 8; ++e) m = fmaxf(m, v[e]);
#pragma unroll
    for (int off = 32; off; off >>= 1) m = fmaxf(m, __shfl_xor(m, off));
    __shared__ float redm[4], reds[4];
    if ((tid & 63) == 0) redm[tid >> 6] = m;
    __syncthreads();
    m = fmaxf(fmaxf(redm[0], redm[1]), fmaxf(redm[2], redm[3]));

    float e8[8];
    float s = 0.f;
#pragma unroll
    for (int e = 0; e < 8; ++e) { e8[e] = __expf(v[e] - m); s += e8[e]; }
#pragma unroll
    for (int off = 32; off; off >>= 1) s += __shfl_xor(s, off);
    if ((tid & 63) == 0) reds[tid >> 6] = s;
    __syncthreads();
    s = reds[0] + reds[1] + reds[2] + reds[3];
    const float inv = 1.f / s;

    uint4 outw;
    unsigned o[4];
#pragma unroll
    for (int c = 0; c < 4; ++c) {
        unsigned lo = f2bf_bits(e8[2 * c] * inv);
        unsigned hi = f2bf_bits(e8[2 * c + 1] * inv);
        o[c] = lo | (hi << 16);
    }
    outw.x = o[0]; outw.y = o[1]; outw.z = o[2]; outw.w = o[3];
    ((uint4*)row)[tid] = outw;
}

// ---------------------------------------------------------------------------
// Weight cast + transpose: in fp32 [K,N] -> out bf16 [N,K]
// ---------------------------------------------------------------------------
__global__ __launch_bounds__(256)
void wcast_t(const float* __restrict__ in, __hip_bfloat16* __restrict__ out,
             int K, int N)
{
    __shared__ float t[32][33];
    const int n0 = blockIdx.x * 32, k0 = blockIdx.y * 32;
    const int tx = threadIdx.x, ty = threadIdx.y;
#pragma unroll
    for (int r = ty; r < 32; r += 8)
        t[r][tx] = in[(long long)(k0 + r) * N + n0 + tx];
    __syncthreads();
#pragma unroll
    for (int r = ty; r < 32; r += 8)
        out[(long long)(n0 + r) * K + k0 + tx] = __float2bfloat16(t[tx][r]);
}

// ---------------------------------------------------------------------------
extern "C" void kernel_launch(void* const* d_in, const int* in_sizes, int n_in,
                              void* d_out, int out_size, void* d_ws, size_t ws_size,
                              hipStream_t stream)
{
    const float* x      = (const float*)d_in[0];
    const float* w_qkv  = (const float*)d_in[1];
    const float* w_proj = (const float*)d_in[2];
    const float* w1     = (const float*)d_in[3];
    const float* w2     = (const float*)d_in[4];
    const float* g1     = (const float*)d_in[5];
    const float* g2     = (const float*)d_in[6];
    float* out = (float*)d_out;
    char* ws = (char*)d_ws;

    const size_t SP_off = 0;                       // S/P bf16 [8,2048,2048] 64MiB
    const size_t h_off  = 0;                       // h bf16 (before S exists)
    const size_t u_off  = 0;                       // u bf16 (after P dead)
    const size_t q_off  = 67108864ull;             // q bf16 -> h2
    const size_t k_off  = 100663296ull;            // k bf16 -> av
    const size_t vT_off = 134217728ull;            // vT bf16 [8,1024,2048]
    const size_t wq_off = 167772160ull;            // 6.29MB
    const size_t wp_off = wq_off + 6291456ull;     // 2.10MB
    const size_t w1_off = wp_off + 2097152ull;     // 4.19MB
    const size_t w2_off = w1_off + 4194304ull;     // 4.19MB
    const size_t NEED   = w2_off + 4194304ull;     // 176 MiB

    if (ws_size < NEED) return;  // guard: fail absmax instead of faulting

    auto bf = [&](size_t off) { return (__hip_bfloat16*)(ws + off); };

    // 1. weights -> bf16 [N,K]
    wcast_t<<<dim3(96, 32), dim3(32, 8), 0, stream>>>(w_qkv,  bf(wq_off), 1024, 3072);
    wcast_t<<<dim3(32, 32), dim3(32, 8), 0, stream>>>(w_proj, bf(wp_off), 1024, 1024);
    wcast_t<<<dim3(64, 32), dim3(32, 8), 0, stream>>>(w1,     bf(w1_off), 1024, 2048);
    wcast_t<<<dim3(32, 64), dim3(32, 8), 0, stream>>>(w2,     bf(w2_off), 2048, 1024);

    // 2. h = rmsnorm(x, g1)
    rmsnorm_kernel<<<16384, 256, 0, stream>>>(x, g1, bf(h_off));

    // 3. fused qkv: q, k, vT = (h @ Wv)^T in one dispatch
    gemm256<6, 0><<<dim3(12, 64, 1), 512, 0, stream>>>(
        bf(h_off), bf(wq_off), bf(q_off), nullptr, bf(k_off), bf(vT_off),
        1024, 1024, 1024, 1024, 0, 0, 0, 1.f);

    // 4. S = q @ k^T * 1/32  (bf16, causal block skip at 256 granularity)
    gemm256<4, 1><<<dim3(8, 8, 8), 512, 0, stream>>>(
        bf(q_off), bf(k_off), bf(SP_off), nullptr, nullptr, nullptr,
        1024, 1024, 1024, 2048,
        (long long)T_DIM * C_DIM, (long long)T_DIM * C_DIM, (long long)T_DIM * T_DIM,
        0.03125f);

    // 5. P = causal softmax(S), in place
    softmax_causal<<<dim3(2048, 8), 256, 0, stream>>>(bf(SP_off));

    // 6. av = P @ V  (vT as Bt, K clipped at diagonal)
    gemm256<0, 2><<<dim3(4, 8, 8), 512, 0, stream>>>(
        bf(SP_off), bf(vT_off), bf(k_off) /*av*/, nullptr, nullptr, nullptr,
        2048, 2048, 2048, 1024,
        (long long)T_DIM * T_DIM, (long long)C_DIM * T_DIM, (long long)T_DIM * C_DIM,
        1.f);

    // 7. x_mid = x + av @ w_proj   (-> d_out)
    gemm256<2, 0><<<dim3(4, 64, 1), 512, 0, stream>>>(
        bf(k_off) /*av*/, bf(wp_off), out, x, nullptr, nullptr,
        1024, 1024, 1024, 1024, 0, 0, 0, 1.f);

    // 8. h2 = rmsnorm(x_mid, g2)   (-> q region)
    rmsnorm_kernel<<<16384, 256, 0, stream>>>(out, g2, bf(q_off));

    // 9. u = silu(h2 @ w1)   (-> SP region, dead)
    gemm256<3, 0><<<dim3(8, 64, 1), 512, 0, stream>>>(
        bf(q_off), bf(w1_off), bf(u_off), nullptr, nullptr, nullptr,
        1024, 1024, 1024, 2048, 0, 0, 0, 1.f);

    // 10. out = x_mid + u @ w2   (in place on d_out)
    gemm256<2, 0><<<dim3(4, 64, 1), 512, 0, stream>>>(
        bf(u_off), bf(w2_off), out, (const float*)out, nullptr, nullptr,
        2048, 2048, 2048, 1024, 0, 0, 0, 1.f);
}

// Round 9
// 583.493 us; speedup vs baseline: 1.0218x; 1.0218x over previous
//
#include <hip/hip_runtime.h>
#include <hip/hip_bf16.h>
#include <stdint.h>

// Transformer block: B=8, T=2048, C=1024, fp32 in/out, bf16 MFMA internally.
// Round 9: UNPINNED tile body. Rounds 5-8 all pinned the scheduler with
// sched_barrier(0) around every wait/barrier (12-16 fences per K-tile) ->
// LDS service and MFMA serialized (25% MfmaUtil, invariant across 4 schedule
// variants = m141 failure mode). This round: one sync point per K-tile,
// zero sched_barrier, compiler-scheduled reads+MFMA interleave, counted
// waits only where correctness needs them (asm memory clobbers fence LDS
// reads from sinking past the barrier; staged loads get a full ~2500-cycle
// tile before anything waits on them).

#define C_DIM 1024
#define T_DIM 2048
#define B_DIM 8

typedef float f32x4 __attribute__((ext_vector_type(4)));
typedef __bf16 bf16x8 __attribute__((ext_vector_type(8)));

typedef const __attribute__((address_space(1))) void gvoid_t;
typedef __attribute__((address_space(3))) void lvoid_t;

__device__ __forceinline__ void gload_lds16(const void* g, void* l) {
    __builtin_amdgcn_global_load_lds((gvoid_t*)g, (lvoid_t*)l, 16, 0, 0);
}

__device__ __forceinline__ unsigned short f2bf_bits(float f) {
    __hip_bfloat16 h = __float2bfloat16(f);
    return *reinterpret_cast<unsigned short*>(&h);
}

// Bijective XCD-chunked remap (m204)
__device__ __forceinline__ void xcd_remap(int& bx, int& by, int& bz) {
    const int gx = gridDim.x, gy = gridDim.y;
    const int nwg = gx * gy * (int)gridDim.z;
    const int orig = bx + gx * (by + gy * bz);
    const int q = nwg >> 3, r = nwg & 7;
    const int xcd = orig & 7, pos = orig >> 3;
    const int neu = (xcd < r ? xcd * (q + 1) : r * (q + 1) + (xcd - r) * q) + pos;
    bx = neu % gx;
    const int t = neu / gx;
    by = t % gy;
    bz = t / gy;
}

// ds-read A fragments (4 mf x 2 ks), wave-row-half hq, dbuf buf
#define RD_A(dst, buf, hq) do { \
    _Pragma("unroll") \
    for (int mf_ = 0; mf_ < 4; ++mf_) { \
        const char* p_ = lds + (buf)*32768 + wrb + (hq)*8192 + mf_*2048; \
        dst[mf_][0] = *(const bf16x8*)(p_ + offk0); \
        dst[mf_][1] = *(const bf16x8*)(p_ + offk1); \
    } \
} while(0)

// ds-read B fragments (2 n2 x 2 ks), wave-col-half nh, dbuf buf
#define RD_B(dst, buf, nh) do { \
    _Pragma("unroll") \
    for (int n2_ = 0; n2_ < 2; ++n2_) { \
        const char* p_ = lds + 65536 + (buf)*32768 + wcb + ((nh)*2 + n2_)*2048; \
        dst[n2_][0] = *(const bf16x8*)(p_ + offk0); \
        dst[n2_][1] = *(const bf16x8*)(p_ + offk1); \
    } \
} while(0)

// 16 MFMA for quadrant (Mh,Nh) from reg sets aS/bS (no fences inside)
#define MMQ(aS, bS, Mh, Nh) do { \
    _Pragma("unroll") \
    for (int m4_ = 0; m4_ < 4; ++m4_) \
    _Pragma("unroll") \
    for (int n2_ = 0; n2_ < 2; ++n2_) \
    _Pragma("unroll") \
    for (int ks_ = 0; ks_ < 2; ++ks_) \
        acc[(Mh)*4 + m4_][(Nh)*2 + n2_] = __builtin_amdgcn_mfma_f32_16x16x32_bf16( \
            aS[m4_][ks_], bS[n2_][ks_], acc[(Mh)*4 + m4_][(Nh)*2 + n2_], 0, 0, 0); \
} while(0)

// stage one 16KB half-tile (2 x gload_lds16 per thread)
#define STA(buf, half, kt) do { \
    const int go_ = aoff + (half)*128*lda + (kt)*64; \
    char* lp_ = ldsw + (buf)*32768 + (half)*16384; \
    gload_lds16(A + go_,            lp_); \
    gload_lds16(A + go_ + 64*lda,   lp_ + 8192); \
} while(0)
#define STB(buf, half, kt) do { \
    const int go_ = boff + (half)*128*ldb + (kt)*64; \
    char* lp_ = ldsw + 65536 + (buf)*32768 + (half)*16384; \
    gload_lds16(Bt + go_,           lp_); \
    gload_lds16(Bt + go_ + 64*ldb,  lp_ + 8192); \
} while(0)

// ---------------------------------------------------------------------------
// One K-tile, single sync point:
//   [compiler-scheduled] 24 ds_reads + 64 MFMA (setprio(1) on MFMA block)
//   lgkmcnt(0)  -- free (reads consumed); memory-clobber fences LDS reads
//   vmcnt(0)    -- free (stage issued 1 tile ago, ~2500cyc > 900 HBM lat)
//   s_barrier   -- publishes staged data, orders restage below vs all reads
//   stage tile t+2 into buf (just-freed)
// ---------------------------------------------------------------------------
#define TILE_BODY(t, STG) do { \
    const int buf_ = (t) & 1; \
    bf16x8 a0[4][2], a1[4][2], b0v[2][2], b1v[2][2]; \
    RD_A(a0, buf_, 0); RD_A(a1, buf_, 1); \
    RD_B(b0v, buf_, 0); RD_B(b1v, buf_, 1); \
    __builtin_amdgcn_s_setprio(1); \
    MMQ(a0, b0v, 0, 0); MMQ(a0, b1v, 0, 1); \
    MMQ(a1, b0v, 1, 0); MMQ(a1, b1v, 1, 1); \
    __builtin_amdgcn_s_setprio(0); \
    asm volatile("s_waitcnt lgkmcnt(0)" ::: "memory"); \
    asm volatile("s_waitcnt vmcnt(0)" ::: "memory"); \
    __builtin_amdgcn_s_barrier(); \
    if (STG) { STB(buf_,0,(t)+2); STB(buf_,1,(t)+2); \
               STA(buf_,0,(t)+2); STA(buf_,1,(t)+2); } \
} while(0)

// ---------------------------------------------------------------------------
// 256x256 GEMM: C[M,N] = A[M,K] x Bt[N,K], bf16 in. BK=64, 8 waves (2Mx4N).
// EPI: 0 bf16; 2 fp32 + residual R (Cout may alias R); 3 bf16 silu;
//      4 bf16*scale; 6 fused qkv route (Cout=q, C2=k, C3=vT[B][C][T]).
// CMODE: 0 none; 1 causal block skip; 2 causal K clip (kmax = m0+256).
// ---------------------------------------------------------------------------
template<int EPI, int CMODE>
__global__ __launch_bounds__(512, 2)
void gemm256(const __hip_bfloat16* A, const __hip_bfloat16* Bt,
             void* Cout, const float* R, void* C2, void* C3,
             int K, int lda, int ldb, int ldc,
             long long sA, long long sB, long long sC, float scale)
{
    int bx = blockIdx.x, by = blockIdx.y, bz = blockIdx.z;
    xcd_remap(bx, by, bz);
    if constexpr (CMODE == 1) { if (bx > by) return; }

    const int tid  = threadIdx.x;
    const int lane = tid & 63, wave = tid >> 6;
    const int l15  = lane & 15, l4 = lane >> 4;
    const int wr   = wave >> 2, wc = wave & 3;      // 2 x 4 wave grid
    const int m0   = by * 256, n0 = bx * 256;
    const int z    = bz;

    A  += (long long)z * sA;
    Bt += (long long)z * sB;

    __shared__ __align__(16) char lds_[131072];     // A [0,64K), B [64K,128K)
    char* lds  = lds_;
    char* ldsw = lds_ + wave * 1024;

    int kmax = K;
    if constexpr (CMODE == 2) { int km = m0 + 256; kmax = km < K ? km : K; }
    const int NT = kmax >> 6;                       // NT >= 4 for all shapes

    // read-side lane offsets: row-local byte = l15*128 + ((ks*4+l4)^(l15&7))*16
    const int offk0 = l15 * 128 + (((l4)     ^ (l15 & 7)) << 4);
    const int offk1 = l15 * 128 + (((4 + l4) ^ (l15 & 7)) << 4);
    const int wrb = wr * 16384, wcb = wc * 8192;

    // staging: thread -> (row = tid>>3, slot = (tid&7)^(row&7)); inverse swizzle on src
    const int rowq  = tid >> 3;
    const int sslot = (tid & 7) ^ (rowq & 7);
    const int aoff  = (m0 + rowq) * lda + sslot * 8;
    const int boff  = (n0 + rowq) * ldb + sslot * 8;

    f32x4 acc[8][4];
#pragma unroll
    for (int i = 0; i < 8; ++i)
#pragma unroll
        for (int j = 0; j < 4; ++j) acc[i][j] = (f32x4){0.f, 0.f, 0.f, 0.f};

    // prologue: stage tiles 0,1; wait tile0 only (tile1's 8 stay in flight)
    STB(0, 0, 0); STB(0, 1, 0); STA(0, 0, 0); STA(0, 1, 0);
    STB(1, 0, 1); STB(1, 1, 1); STA(1, 0, 1); STA(1, 1, 1);
    asm volatile("s_waitcnt vmcnt(8)" ::: "memory");
    __builtin_amdgcn_s_barrier();

    int t = 0;
    for (; t < NT - 2; ++t) TILE_BODY(t, true);
    for (; t < NT; ++t)     TILE_BODY(t, false);

    asm volatile("s_waitcnt vmcnt(0)" ::: "memory");

    // epilogue: row = m0 + wr*128 + mf*16 + l4*4 + r ; col = n0 + wc*64 + nf*16 + l15
    const long long cbase = (long long)z * sC;
#pragma unroll
    for (int mf = 0; mf < 8; ++mf) {
        const int rbase = m0 + wr * 128 + mf * 16 + l4 * 4;
#pragma unroll
        for (int nf = 0; nf < 4; ++nf) {
            const int col = n0 + wc * 64 + nf * 16 + l15;
#pragma unroll
            for (int r = 0; r < 4; ++r) {
                const float v = acc[mf][nf][r];
                const int row = rbase + r;
                if constexpr (EPI == 6) {
                    const int seg = col >> 10, ncol = col & 1023;
                    if (seg == 0) {
                        ((__hip_bfloat16*)Cout)[(long long)row * 1024 + ncol] =
                            __float2bfloat16(v);
                    } else if (seg == 1) {
                        ((__hip_bfloat16*)C2)[(long long)row * 1024 + ncol] =
                            __float2bfloat16(v);
                    } else {
                        const int b = row >> 11, tt = row & 2047;
                        ((__hip_bfloat16*)C3)[((long long)b * C_DIM + ncol) * T_DIM + tt] =
                            __float2bfloat16(v);
                    }
                } else {
                    const long long idx = cbase + (long long)row * ldc + col;
                    if constexpr (EPI == 0) {
                        ((__hip_bfloat16*)Cout)[idx] = __float2bfloat16(v);
                    } else if constexpr (EPI == 2) {
                        ((float*)Cout)[idx] = v + R[idx];
                    } else if constexpr (EPI == 3) {
                        const float s = v / (1.f + __expf(-v));
                        ((__hip_bfloat16*)Cout)[idx] = __float2bfloat16(s);
                    } else { // EPI == 4
                        ((__hip_bfloat16*)Cout)[idx] = __float2bfloat16(v * scale);
                    }
                }
            }
        }
    }
}

// ---------------------------------------------------------------------------
// RMSNorm: one block per row of C_DIM, fp32 in -> bf16 out
// ---------------------------------------------------------------------------
__global__ __launch_bounds__(256)
void rmsnorm_kernel(const float* __restrict__ x, const float* __restrict__ g,
                    __hip_bfloat16* __restrict__ out)
{
    const long long row = blockIdx.x;
    const int tid = threadIdx.x;
    const float4 v = ((const float4*)(x + row * C_DIM))[tid];
    float ss = v.x * v.x + v.y * v.y + v.z * v.z + v.w * v.w;
#pragma unroll
    for (int off = 32; off; off >>= 1) ss += __shfl_xor(ss, off);
    __shared__ float red[4];
    if ((tid & 63) == 0) red[tid >> 6] = ss;
    __syncthreads();
    ss = red[0] + red[1] + red[2] + red[3];
    const float sc = rsqrtf(ss * (1.0f / C_DIM) + 1e-6f);
    const float4 gv = ((const float4*)g)[tid];
    ushort4 u;
    u.x = f2bf_bits(v.x * sc * gv.x);
    u.y = f2bf_bits(v.y * sc * gv.y);
    u.z = f2bf_bits(v.z * sc * gv.z);
    u.w = f2bf_bits(v.w * sc * gv.w);
    *(ushort4*)(out + row * C_DIM + tid * 4) = u;
}

// ---------------------------------------------------------------------------
// Causal softmax, IN PLACE on bf16 S [B,T,T] -> P bf16 (zeros above diagonal).
// ---------------------------------------------------------------------------
__global__ __launch_bounds__(256)
void softmax_causal(__hip_bfloat16* __restrict__ SP)
{
    const int i = blockIdx.x, b = blockIdx.y;
    __hip_bfloat16* row = SP + ((long long)b * T_DIM + i) * T_DIM;
    const int tid = threadIdx.x;
    const int jbase = tid * 8;

    uint4 raw = ((const uint4*)row)[tid];
    float v[8];
    const unsigned w[4] = {raw.x, raw.y, raw.z, raw.w};
#pragma unroll
    for (int c = 0; c < 4; ++c) {
        unsigned lo = w[c] << 16;
        unsigned hi = w[c] & 0xFFFF0000u;
        v[2 * c]     = __uint_as_float(lo);
        v[2 * c + 1] = __uint_as_float(hi);
    }
#pragma unroll
    for (int e = 0; e < 8; ++e)
        if (jbase + e > i) v[e] = -1e30f;

    float m = v[0];
#pragma unroll
    for (int e = 1; e < 8; ++e) m = fmaxf(m, v[e]);
#pragma unroll
    for (int off = 32; off; off >>= 1) m = fmaxf(m, __shfl_xor(m, off));
    __shared__ float redm[4], reds[4];
    if ((tid & 63) == 0) redm[tid >> 6] = m;
    __syncthreads();
    m = fmaxf(fmaxf(redm[0], redm[1]), fmaxf(redm[2], redm[3]));

    float e8[8];
    float s = 0.f;
#pragma unroll
    for (int e = 0; e < 8; ++e) { e8[e] = __expf(v[e] - m); s += e8[e]; }
#pragma unroll
    for (int off = 32; off; off >>= 1) s += __shfl_xor(s, off);
    if ((tid & 63) == 0) reds[tid >> 6] = s;
    __syncthreads();
    s = reds[0] + reds[1] + reds[2] + reds[3];
    const float inv = 1.f / s;

    uint4 outw;
    unsigned o[4];
#pragma unroll
    for (int c = 0; c < 4; ++c) {
        unsigned lo = f2bf_bits(e8[2 * c] * inv);
        unsigned hi = f2bf_bits(e8[2 * c + 1] * inv);
        o[c] = lo | (hi << 16);
    }
    outw.x = o[0]; outw.y = o[1]; outw.z = o[2]; outw.w = o[3];
    ((uint4*)row)[tid] = outw;
}

// ---------------------------------------------------------------------------
// Weight cast + transpose: in fp32 [K,N] -> out bf16 [N,K]
// ---------------------------------------------------------------------------
__global__ __launch_bounds__(256)
void wcast_t(const float* __restrict__ in, __hip_bfloat16* __restrict__ out,
             int K, int N)
{
    __shared__ float t[32][33];
    const int n0 = blockIdx.x * 32, k0 = blockIdx.y * 32;
    const int tx = threadIdx.x, ty = threadIdx.y;
#pragma unroll
    for (int r = ty; r < 32; r += 8)
        t[r][tx] = in[(long long)(k0 + r) * N + n0 + tx];
    __syncthreads();
#pragma unroll
    for (int r = ty; r < 32; r += 8)
        out[(long long)(n0 + r) * K + k0 + tx] = __float2bfloat16(t[tx][r]);
}

// ---------------------------------------------------------------------------
extern "C" void kernel_launch(void* const* d_in, const int* in_sizes, int n_in,
                              void* d_out, int out_size, void* d_ws, size_t ws_size,
                              hipStream_t stream)
{
    const float* x      = (const float*)d_in[0];
    const float* w_qkv  = (const float*)d_in[1];
    const float* w_proj = (const float*)d_in[2];
    const float* w1     = (const float*)d_in[3];
    const float* w2     = (const float*)d_in[4];
    const float* g1     = (const float*)d_in[5];
    const float* g2     = (const float*)d_in[6];
    float* out = (float*)d_out;
    char* ws = (char*)d_ws;

    const size_t SP_off = 0;                       // S/P bf16 [8,2048,2048] 64MiB
    const size_t h_off  = 0;                       // h bf16 (before S exists)
    const size_t u_off  = 0;                       // u bf16 (after P dead)
    const size_t q_off  = 67108864ull;             // q bf16 -> h2
    const size_t k_off  = 100663296ull;            // k bf16 -> av
    const size_t vT_off = 134217728ull;            // vT bf16 [8,1024,2048]
    const size_t wq_off = 167772160ull;            // 6.29MB
    const size_t wp_off = wq_off + 6291456ull;     // 2.10MB
    const size_t w1_off = wp_off + 2097152ull;     // 4.19MB
    const size_t w2_off = w1_off + 4194304ull;     // 4.19MB
    const size_t NEED   = w2_off + 4194304ull;     // 176 MiB

    if (ws_size < NEED) return;  // guard: fail absmax instead of faulting

    auto bf = [&](size_t off) { return (__hip_bfloat16*)(ws + off); };

    // 1. weights -> bf16 [N,K]
    wcast_t<<<dim3(96, 32), dim3(32, 8), 0, stream>>>(w_qkv,  bf(wq_off), 1024, 3072);
    wcast_t<<<dim3(32, 32), dim3(32, 8), 0, stream>>>(w_proj, bf(wp_off), 1024, 1024);
    wcast_t<<<dim3(64, 32), dim3(32, 8), 0, stream>>>(w1,     bf(w1_off), 1024, 2048);
    wcast_t<<<dim3(32, 64), dim3(32, 8), 0, stream>>>(w2,     bf(w2_off), 2048, 1024);

    // 2. h = rmsnorm(x, g1)
    rmsnorm_kernel<<<16384, 256, 0, stream>>>(x, g1, bf(h_off));

    // 3. fused qkv: q, k, vT = (h @ Wv)^T in one dispatch
    gemm256<6, 0><<<dim3(12, 64, 1), 512, 0, stream>>>(
        bf(h_off), bf(wq_off), bf(q_off), nullptr, bf(k_off), bf(vT_off),
        1024, 1024, 1024, 1024, 0, 0, 0, 1.f);

    // 4. S = q @ k^T * 1/32  (bf16, causal block skip at 256 granularity)
    gemm256<4, 1><<<dim3(8, 8, 8), 512, 0, stream>>>(
        bf(q_off), bf(k_off), bf(SP_off), nullptr, nullptr, nullptr,
        1024, 1024, 1024, 2048,
        (long long)T_DIM * C_DIM, (long long)T_DIM * C_DIM, (long long)T_DIM * T_DIM,
        0.03125f);

    // 5. P = causal softmax(S), in place
    softmax_causal<<<dim3(2048, 8), 256, 0, stream>>>(bf(SP_off));

    // 6. av = P @ V  (vT as Bt, K clipped at diagonal)
    gemm256<0, 2><<<dim3(4, 8, 8), 512, 0, stream>>>(
        bf(SP_off), bf(vT_off), bf(k_off) /*av*/, nullptr, nullptr, nullptr,
        2048, 2048, 2048, 1024,
        (long long)T_DIM * T_DIM, (long long)C_DIM * T_DIM, (long long)T_DIM * C_DIM,
        1.f);

    // 7. x_mid = x + av @ w_proj   (-> d_out)
    gemm256<2, 0><<<dim3(4, 64, 1), 512, 0, stream>>>(
        bf(k_off) /*av*/, bf(wp_off), out, x, nullptr, nullptr,
        1024, 1024, 1024, 1024, 0, 0, 0, 1.f);

    // 8. h2 = rmsnorm(x_mid, g2)   (-> q region)
    rmsnorm_kernel<<<16384, 256, 0, stream>>>(out, g2, bf(q_off));

    // 9. u = silu(h2 @ w1)   (-> SP region, dead)
    gemm256<3, 0><<<dim3(8, 64, 1), 512, 0, stream>>>(
        bf(q_off), bf(w1_off), bf(u_off), nullptr, nullptr, nullptr,
        1024, 1024, 1024, 2048, 0, 0, 0, 1.f);

    // 10. out = x_mid + u @ w2   (in place on d_out)
    gemm256<2, 0><<<dim3(4, 64, 1), 512, 0, stream>>>(
        bf(u_off), bf(w2_off), out, (const float*)out, nullptr, nullptr,
        2048, 2048, 2048, 1024, 0, 0, 0, 1.f);
}

// Round 10
// 549.318 us; speedup vs baseline: 1.0854x; 1.0622x over previous
//
#include <hip/hip_runtime.h>
#include <hip/hip_bf16.h>
#include <stdint.h>

// Transformer block: B=8, T=2048, C=1024, fp32 in/out, bf16 MFMA internally.
// Round 10: controlled A/B round.
//  - QKV split into three identical-shape GEMMs:
//      q = gemm256_w32 (32x32x16 MFMA fragments)   <- VARIANT B
//      k = gemm256     (16x16x32, round-9 body)    <- VARIANT A (control)
//      v = gemm256 EPI5 (control + vT scatter epilogue)
//  - S and AV moved to the verified round-4 128x128 kernel (32 KiB LDS,
//    ~5 resident blocks/CU; causal skip/clip at 128 granularity).

#define C_DIM 1024
#define T_DIM 2048
#define B_DIM 8

typedef float f32x4  __attribute__((ext_vector_type(4)));
typedef float f32x16 __attribute__((ext_vector_type(16)));
typedef __bf16 bf16x8 __attribute__((ext_vector_type(8)));

typedef const __attribute__((address_space(1))) void gvoid_t;
typedef __attribute__((address_space(3))) void lvoid_t;

__device__ __forceinline__ void gload_lds16(const void* g, void* l) {
    __builtin_amdgcn_global_load_lds((gvoid_t*)g, (lvoid_t*)l, 16, 0, 0);
}

__device__ __forceinline__ unsigned short f2bf_bits(float f) {
    __hip_bfloat16 h = __float2bfloat16(f);
    return *reinterpret_cast<unsigned short*>(&h);
}

// Bijective XCD-chunked remap (m204)
__device__ __forceinline__ void xcd_remap(int& bx, int& by, int& bz) {
    const int gx = gridDim.x, gy = gridDim.y;
    const int nwg = gx * gy * (int)gridDim.z;
    const int orig = bx + gx * (by + gy * bz);
    const int q = nwg >> 3, r = nwg & 7;
    const int xcd = orig & 7, pos = orig >> 3;
    const int neu = (xcd < r ? xcd * (q + 1) : r * (q + 1) + (xcd - r) * q) + pos;
    bx = neu % gx;
    const int t = neu / gx;
    by = t % gy;
    bz = t / gy;
}

// ===========================================================================
// VARIANT A: 256x256, 16x16x32 fragments, round-9 unpinned single-sync body.
// ===========================================================================
#define RD_A(dst, buf, hq) do { \
    _Pragma("unroll") \
    for (int mf_ = 0; mf_ < 4; ++mf_) { \
        const char* p_ = lds + (buf)*32768 + wrb + (hq)*8192 + mf_*2048; \
        dst[mf_][0] = *(const bf16x8*)(p_ + offk0); \
        dst[mf_][1] = *(const bf16x8*)(p_ + offk1); \
    } \
} while(0)

#define RD_B(dst, buf, nh) do { \
    _Pragma("unroll") \
    for (int n2_ = 0; n2_ < 2; ++n2_) { \
        const char* p_ = lds + 65536 + (buf)*32768 + wcb + ((nh)*2 + n2_)*2048; \
        dst[n2_][0] = *(const bf16x8*)(p_ + offk0); \
        dst[n2_][1] = *(const bf16x8*)(p_ + offk1); \
    } \
} while(0)

#define MMQ(aS, bS, Mh, Nh) do { \
    _Pragma("unroll") \
    for (int m4_ = 0; m4_ < 4; ++m4_) \
    _Pragma("unroll") \
    for (int n2_ = 0; n2_ < 2; ++n2_) \
    _Pragma("unroll") \
    for (int ks_ = 0; ks_ < 2; ++ks_) \
        acc[(Mh)*4 + m4_][(Nh)*2 + n2_] = __builtin_amdgcn_mfma_f32_16x16x32_bf16( \
            aS[m4_][ks_], bS[n2_][ks_], acc[(Mh)*4 + m4_][(Nh)*2 + n2_], 0, 0, 0); \
} while(0)

#define STA(buf, half, kt) do { \
    const int go_ = aoff + (half)*128*lda + (kt)*64; \
    char* lp_ = ldsw + (buf)*32768 + (half)*16384; \
    gload_lds16(A + go_,            lp_); \
    gload_lds16(A + go_ + 64*lda,   lp_ + 8192); \
} while(0)
#define STB(buf, half, kt) do { \
    const int go_ = boff + (half)*128*ldb + (kt)*64; \
    char* lp_ = ldsw + 65536 + (buf)*32768 + (half)*16384; \
    gload_lds16(Bt + go_,           lp_); \
    gload_lds16(Bt + go_ + 64*ldb,  lp_ + 8192); \
} while(0)

#define TILE_BODY(t, STG) do { \
    const int buf_ = (t) & 1; \
    bf16x8 a0[4][2], a1[4][2], b0v[2][2], b1v[2][2]; \
    RD_A(a0, buf_, 0); RD_A(a1, buf_, 1); \
    RD_B(b0v, buf_, 0); RD_B(b1v, buf_, 1); \
    __builtin_amdgcn_s_setprio(1); \
    MMQ(a0, b0v, 0, 0); MMQ(a0, b1v, 0, 1); \
    MMQ(a1, b0v, 1, 0); MMQ(a1, b1v, 1, 1); \
    __builtin_amdgcn_s_setprio(0); \
    asm volatile("s_waitcnt lgkmcnt(0)" ::: "memory"); \
    asm volatile("s_waitcnt vmcnt(0)" ::: "memory"); \
    __builtin_amdgcn_s_barrier(); \
    if (STG) { STB(buf_,0,(t)+2); STB(buf_,1,(t)+2); \
               STA(buf_,0,(t)+2); STA(buf_,1,(t)+2); } \
} while(0)

// EPI: 0 bf16; 2 fp32 + residual R (Cout may alias R); 3 bf16 silu;
//      5 bf16 transposed store into vT[B][C][T] (row = b*T+t, col = C idx).
template<int EPI>
__global__ __launch_bounds__(512, 2)
void gemm256(const __hip_bfloat16* A, const __hip_bfloat16* Bt,
             void* Cout, const float* R,
             int K, int lda, int ldb, int ldc)
{
    int bx = blockIdx.x, by = blockIdx.y, bz = blockIdx.z;
    xcd_remap(bx, by, bz);

    const int tid  = threadIdx.x;
    const int lane = tid & 63, wave = tid >> 6;
    const int l15  = lane & 15, l4 = lane >> 4;
    const int wr   = wave >> 2, wc = wave & 3;
    const int m0   = by * 256, n0 = bx * 256;

    __shared__ __align__(16) char lds_[131072];
    char* lds  = lds_;
    char* ldsw = lds_ + wave * 1024;

    const int NT = K >> 6;

    const int offk0 = l15 * 128 + (((l4)     ^ (l15 & 7)) << 4);
    const int offk1 = l15 * 128 + (((4 + l4) ^ (l15 & 7)) << 4);
    const int wrb = wr * 16384, wcb = wc * 8192;

    const int rowq  = tid >> 3;
    const int sslot = (tid & 7) ^ (rowq & 7);
    const int aoff  = (m0 + rowq) * lda + sslot * 8;
    const int boff  = (n0 + rowq) * ldb + sslot * 8;

    f32x4 acc[8][4];
#pragma unroll
    for (int i = 0; i < 8; ++i)
#pragma unroll
        for (int j = 0; j < 4; ++j) acc[i][j] = (f32x4){0.f, 0.f, 0.f, 0.f};

    STB(0, 0, 0); STB(0, 1, 0); STA(0, 0, 0); STA(0, 1, 0);
    STB(1, 0, 1); STB(1, 1, 1); STA(1, 0, 1); STA(1, 1, 1);
    asm volatile("s_waitcnt vmcnt(8)" ::: "memory");
    __builtin_amdgcn_s_barrier();

    int t = 0;
    for (; t < NT - 2; ++t) TILE_BODY(t, true);
    for (; t < NT; ++t)     TILE_BODY(t, false);

    asm volatile("s_waitcnt vmcnt(0)" ::: "memory");

#pragma unroll
    for (int mf = 0; mf < 8; ++mf) {
        const int rbase = m0 + wr * 128 + mf * 16 + l4 * 4;
#pragma unroll
        for (int nf = 0; nf < 4; ++nf) {
            const int col = n0 + wc * 64 + nf * 16 + l15;
#pragma unroll
            for (int r = 0; r < 4; ++r) {
                const float v = acc[mf][nf][r];
                const int row = rbase + r;
                if constexpr (EPI == 5) {
                    ((__hip_bfloat16*)Cout)[((long long)(row >> 11) * C_DIM + col) * T_DIM
                                            + (row & 2047)] = __float2bfloat16(v);
                } else {
                    const long long idx = (long long)row * ldc + col;
                    if constexpr (EPI == 0) {
                        ((__hip_bfloat16*)Cout)[idx] = __float2bfloat16(v);
                    } else if constexpr (EPI == 2) {
                        ((float*)Cout)[idx] = v + R[idx];
                    } else { // EPI == 3
                        const float s = v / (1.f + __expf(-v));
                        ((__hip_bfloat16*)Cout)[idx] = __float2bfloat16(s);
                    }
                }
            }
        }
    }
}

// ===========================================================================
// VARIANT B: 256x256, 32x32x16 fragments, same staging/swizzle/sync body.
// Per wave 128x64 = 4 Mfrags(32) x 2 Nfrags(32); acc 8 x f32x16 = 128 VGPR.
// Read: G[row][slot], slot = ks*2 + (lane>>5) -> LDS slot ^ (row&7).
// ===========================================================================
__global__ __launch_bounds__(512, 2)
void gemm256_w32(const __hip_bfloat16* A, const __hip_bfloat16* Bt,
                 void* Cout, int K, int lda, int ldb, int ldc)
{
    int bx = blockIdx.x, by = blockIdx.y, bz = blockIdx.z;
    xcd_remap(bx, by, bz);

    const int tid  = threadIdx.x;
    const int lane = tid & 63, wave = tid >> 6;
    const int l31  = lane & 31, l5 = lane >> 5;
    const int wr   = wave >> 2, wc = wave & 3;
    const int m0   = by * 256, n0 = bx * 256;

    __shared__ __align__(16) char lds_[131072];
    char* lds  = lds_;
    char* ldsw = lds_ + wave * 1024;

    const int NT = K >> 6;

    const int rowq  = tid >> 3;
    const int sslot = (tid & 7) ^ (rowq & 7);
    const int aoff  = (m0 + rowq) * lda + sslot * 8;
    const int boff  = (n0 + rowq) * ldb + sslot * 8;

    f32x16 acc[4][2];
#pragma unroll
    for (int i = 0; i < 4; ++i)
#pragma unroll
        for (int j = 0; j < 2; ++j)
#pragma unroll
            for (int e = 0; e < 16; ++e) acc[i][j][e] = 0.f;

    // per-fragment row/col and swizzled in-row byte offsets (compile-time mf/nf/ks)
    const int arowl = l31 & 7;   // row&7 for all A frags (bases are mult of 8)

    STB(0, 0, 0); STB(0, 1, 0); STA(0, 0, 0); STA(0, 1, 0);
    STB(1, 0, 1); STB(1, 1, 1); STA(1, 0, 1); STA(1, 1, 1);
    asm volatile("s_waitcnt vmcnt(8)" ::: "memory");
    __builtin_amdgcn_s_barrier();

    for (int t = 0; t < NT; ++t) {
        const int buf_ = t & 1;
        bf16x8 aR[4][4], bR[2][4];
#pragma unroll
        for (int mf = 0; mf < 4; ++mf) {
            const int arow = wr * 128 + mf * 32 + l31;
            const char* p_ = lds + buf_ * 32768 + arow * 128;
#pragma unroll
            for (int ks = 0; ks < 4; ++ks)
                aR[mf][ks] = *(const bf16x8*)(p_ + ((((ks << 1) | l5) ^ arowl) << 4));
        }
#pragma unroll
        for (int nf = 0; nf < 2; ++nf) {
            const int bcol = wc * 64 + nf * 32 + l31;
            const char* p_ = lds + 65536 + buf_ * 32768 + bcol * 128;
#pragma unroll
            for (int ks = 0; ks < 4; ++ks)
                bR[nf][ks] = *(const bf16x8*)(p_ + ((((ks << 1) | l5) ^ arowl) << 4));
        }
        __builtin_amdgcn_s_setprio(1);
#pragma unroll
        for (int mf = 0; mf < 4; ++mf)
#pragma unroll
            for (int nf = 0; nf < 2; ++nf)
#pragma unroll
                for (int ks = 0; ks < 4; ++ks)
                    acc[mf][nf] = __builtin_amdgcn_mfma_f32_32x32x16_bf16(
                        aR[mf][ks], bR[nf][ks], acc[mf][nf], 0, 0, 0);
        __builtin_amdgcn_s_setprio(0);
        asm volatile("s_waitcnt lgkmcnt(0)" ::: "memory");
        asm volatile("s_waitcnt vmcnt(0)" ::: "memory");
        __builtin_amdgcn_s_barrier();
        if (t + 2 < NT) {
            STB(buf_, 0, t + 2); STB(buf_, 1, t + 2);
            STA(buf_, 0, t + 2); STA(buf_, 1, t + 2);
        }
    }
    asm volatile("s_waitcnt vmcnt(0)" ::: "memory");

    // C/D: col = lane&31, row = (reg&3) + 8*(reg>>2) + 4*(lane>>5)  [m74/m101]
#pragma unroll
    for (int mf = 0; mf < 4; ++mf)
#pragma unroll
        for (int nf = 0; nf < 2; ++nf) {
            const int col = n0 + wc * 64 + nf * 32 + l31;
#pragma unroll
            for (int reg = 0; reg < 16; ++reg) {
                const int row = m0 + wr * 128 + mf * 32
                              + (reg & 3) + 8 * (reg >> 2) + 4 * l5;
                ((__hip_bfloat16*)Cout)[(long long)row * ldc + col] =
                    __float2bfloat16(acc[mf][nf][reg]);
            }
        }
}

// ===========================================================================
// 128x128 kernel (round-4 verbatim core): BK=32, 4 waves, dbuf 32 KiB,
// 4-chunk XOR swizzle.  EPI: 0 bf16; 4 bf16*scale.
// CMODE: 1 causal block skip; 2 causal K clip (kmax = m0+128).
// ===========================================================================
template<int EPI, int CMODE>
__global__ __launch_bounds__(256)
void gemm128(const __hip_bfloat16* A, const __hip_bfloat16* Bt,
             void* Cout, int K, int lda, int ldb, int ldc,
             long long sA, long long sB, long long sC, float scale)
{
    int bx = blockIdx.x, by = blockIdx.y, bz = blockIdx.z;
    xcd_remap(bx, by, bz);
    if constexpr (CMODE == 1) { if (bx > by) return; }

    const int tid  = threadIdx.x;
    const int lane = tid & 63, wave = tid >> 6;
    const int l15  = lane & 15, l4 = lane >> 4;
    const int wr   = wave >> 1, wc = wave & 1;
    const int m0   = by * 128, n0 = bx * 128;
    const int z    = bz;

    A  += (long long)z * sA;
    Bt += (long long)z * sB;

    __shared__ __align__(16) short As[2][128 * 32];
    __shared__ __align__(16) short Bs[2][128 * 32];

    int kmax = K;
    if constexpr (CMODE == 2) { int km = m0 + 128; kmax = km < K ? km : K; }

    f32x4 acc[4][4];
#pragma unroll
    for (int i = 0; i < 4; ++i)
#pragma unroll
        for (int j = 0; j < 4; ++j) acc[i][j] = (f32x4){0.f, 0.f, 0.f, 0.f};

    const int srow  = wave * 32 + (lane >> 2);
    const int sbyte = (((lane & 3) ^ ((lane >> 2) & 3))) << 4;
    const char* Ag = (const char*)(A  + (long long)(m0 + srow) * lda) + sbyte;
    const char* Bg = (const char*)(Bt + (long long)(n0 + srow) * ldb) + sbyte;
    const long long astep = (long long)16 * lda * 2;
    const long long bstep = (long long)16 * ldb * 2;
    char* AsW[2] = {(char*)As[0] + wave * 2048, (char*)As[1] + wave * 2048};
    char* BsW[2] = {(char*)Bs[0] + wave * 2048, (char*)Bs[1] + wave * 2048};

    auto stage = [&](int buf, int k0) {
        const char* ag = Ag + (long long)k0 * 2;
        const char* bg = Bg + (long long)k0 * 2;
        gload_lds16(ag,         AsW[buf]);
        gload_lds16(ag + astep, AsW[buf] + 1024);
        gload_lds16(bg,         BsW[buf]);
        gload_lds16(bg + bstep, BsW[buf] + 1024);
    };

    const int cs16 = ((l4 ^ (l15 & 3)) << 4);

    stage(0, 0);
    __syncthreads();

    for (int k0 = 0; k0 < kmax; k0 += 32) {
        const int buf = (k0 >> 5) & 1;
        if (k0 + 32 < kmax) stage(buf ^ 1, k0 + 32);

        const char* Ac = (const char*)As[buf];
        const char* Bc = (const char*)Bs[buf];
        bf16x8 af[4], bfr[4];
#pragma unroll
        for (int mi = 0; mi < 4; ++mi) {
            int row = wr * 64 + mi * 16 + l15;
            af[mi] = *(const bf16x8*)(Ac + row * 64 + cs16);
        }
#pragma unroll
        for (int ni = 0; ni < 4; ++ni) {
            int col = wc * 64 + ni * 16 + l15;
            bfr[ni] = *(const bf16x8*)(Bc + col * 64 + cs16);
        }
#pragma unroll
        for (int mi = 0; mi < 4; ++mi)
#pragma unroll
            for (int ni = 0; ni < 4; ++ni)
                acc[mi][ni] = __builtin_amdgcn_mfma_f32_16x16x32_bf16(
                    af[mi], bfr[ni], acc[mi][ni], 0, 0, 0);

        __syncthreads();
    }

    const long long cbase = (long long)z * sC;
#pragma unroll
    for (int mi = 0; mi < 4; ++mi) {
        const int rbase = m0 + wr * 64 + mi * 16 + l4 * 4;
#pragma unroll
        for (int ni = 0; ni < 4; ++ni) {
            const int col = n0 + wc * 64 + ni * 16 + l15;
#pragma unroll
            for (int r = 0; r < 4; ++r) {
                const long long idx = cbase + (long long)(rbase + r) * ldc + col;
                const float v = acc[mi][ni][r];
                if constexpr (EPI == 0) {
                    ((__hip_bfloat16*)Cout)[idx] = __float2bfloat16(v);
                } else { // EPI == 4
                    ((__hip_bfloat16*)Cout)[idx] = __float2bfloat16(v * scale);
                }
            }
        }
    }
}

// ---------------------------------------------------------------------------
// RMSNorm: one block per row of C_DIM, fp32 in -> bf16 out
// ---------------------------------------------------------------------------
__global__ __launch_bounds__(256)
void rmsnorm_kernel(const float* __restrict__ x, const float* __restrict__ g,
                    __hip_bfloat16* __restrict__ out)
{
    const long long row = blockIdx.x;
    const int tid = threadIdx.x;
    const float4 v = ((const float4*)(x + row * C_DIM))[tid];
    float ss = v.x * v.x + v.y * v.y + v.z * v.z + v.w * v.w;
#pragma unroll
    for (int off = 32; off; off >>= 1) ss += __shfl_xor(ss, off);
    __shared__ float red[4];
    if ((tid & 63) == 0) red[tid >> 6] = ss;
    __syncthreads();
    ss = red[0] + red[1] + red[2] + red[3];
    const float sc = rsqrtf(ss * (1.0f / C_DIM) + 1e-6f);
    const float4 gv = ((const float4*)g)[tid];
    ushort4 u;
    u.x = f2bf_bits(v.x * sc * gv.x);
    u.y = f2bf_bits(v.y * sc * gv.y);
    u.z = f2bf_bits(v.z * sc * gv.z);
    u.w = f2bf_bits(v.w * sc * gv.w);
    *(ushort4*)(out + row * C_DIM + tid * 4) = u;
}

// ---------------------------------------------------------------------------
// Causal softmax, IN PLACE on bf16 S [B,T,T] -> P bf16 (zeros above diagonal).
// ---------------------------------------------------------------------------
__global__ __launch_bounds__(256)
void softmax_causal(__hip_bfloat16* __restrict__ SP)
{
    const int i = blockIdx.x, b = blockIdx.y;
    __hip_bfloat16* row = SP + ((long long)b * T_DIM + i) * T_DIM;
    const int tid = threadIdx.x;
    const int jbase = tid * 8;

    uint4 raw = ((const uint4*)row)[tid];
    float v[8];
    const unsigned w[4] = {raw.x, raw.y, raw.z, raw.w};
#pragma unroll
    for (int c = 0; c < 4; ++c) {
        unsigned lo = w[c] << 16;
        unsigned hi = w[c] & 0xFFFF0000u;
        v[2 * c]     = __uint_as_float(lo);
        v[2 * c + 1] = __uint_as_float(hi);
    }
#pragma unroll
    for (int e = 0; e < 8; ++e)
        if (jbase + e > i) v[e] = -1e30f;

    float m = v[0];
#pragma unroll
    for (int e = 1; e < 8; ++e) m = fmaxf(m, v[e]);
#pragma unroll
    for (int off = 32; off; off >>= 1) m = fmaxf(m, __shfl_xor(m, off));
    __shared__ float redm[4], reds[4];
    if ((tid & 63) == 0) redm[tid >> 6] = m;
    __syncthreads();
    m = fmaxf(fmaxf(redm[0], redm[1]), fmaxf(redm[2], redm[3]));

    float e8[8];
    float s = 0.f;
#pragma unroll
    for (int e = 0; e < 8; ++e) { e8[e] = __expf(v[e] - m); s += e8[e]; }
#pragma unroll
    for (int off = 32; off; off >>= 1) s += __shfl_xor(s, off);
    if ((tid & 63) == 0) reds[tid >> 6] = s;
    __syncthreads();
    s = reds[0] + reds[1] + reds[2] + reds[3];
    const float inv = 1.f / s;

    uint4 outw;
    unsigned o[4];
#pragma unroll
    for (int c = 0; c < 4; ++c) {
        unsigned lo = f2bf_bits(e8[2 * c] * inv);
        unsigned hi = f2bf_bits(e8[2 * c + 1] * inv);
        o[c] = lo | (hi << 16);
    }
    outw.x = o[0]; outw.y = o[1]; outw.z = o[2]; outw.w = o[3];
    ((uint4*)row)[tid] = outw;
}

// ---------------------------------------------------------------------------
// Weight cast + transpose: in fp32 [K,N] -> out bf16 [N,K]
// ---------------------------------------------------------------------------
__global__ __launch_bounds__(256)
void wcast_t(const float* __restrict__ in, __hip_bfloat16* __restrict__ out,
             int K, int N)
{
    __shared__ float t[32][33];
    const int n0 = blockIdx.x * 32, k0 = blockIdx.y * 32;
    const int tx = threadIdx.x, ty = threadIdx.y;
#pragma unroll
    for (int r = ty; r < 32; r += 8)
        t[r][tx] = in[(long long)(k0 + r) * N + n0 + tx];
    __syncthreads();
#pragma unroll
    for (int r = ty; r < 32; r += 8)
        out[(long long)(n0 + r) * K + k0 + tx] = __float2bfloat16(t[tx][r]);
}

// ---------------------------------------------------------------------------
extern "C" void kernel_launch(void* const* d_in, const int* in_sizes, int n_in,
                              void* d_out, int out_size, void* d_ws, size_t ws_size,
                              hipStream_t stream)
{
    const float* x      = (const float*)d_in[0];
    const float* w_qkv  = (const float*)d_in[1];
    const float* w_proj = (const float*)d_in[2];
    const float* w1     = (const float*)d_in[3];
    const float* w2     = (const float*)d_in[4];
    const float* g1     = (const float*)d_in[5];
    const float* g2     = (const float*)d_in[6];
    float* out = (float*)d_out;
    char* ws = (char*)d_ws;

    const size_t SP_off = 0;                       // S/P bf16 [8,2048,2048] 64MiB
    const size_t h_off  = 0;                       // h bf16 (before S exists)
    const size_t u_off  = 0;                       // u bf16 (after P dead)
    const size_t q_off  = 67108864ull;             // q bf16 -> h2
    const size_t k_off  = 100663296ull;            // k bf16 -> av
    const size_t vT_off = 134217728ull;            // vT bf16 [8,1024,2048]
    const size_t wq_off = 167772160ull;            // 6.29MB
    const size_t wp_off = wq_off + 6291456ull;     // 2.10MB
    const size_t w1_off = wp_off + 2097152ull;     // 4.19MB
    const size_t w2_off = w1_off + 4194304ull;     // 4.19MB
    const size_t NEED   = w2_off + 4194304ull;     // 176 MiB

    if (ws_size < NEED) return;  // guard: fail absmax instead of faulting

    auto bf = [&](size_t off) { return (__hip_bfloat16*)(ws + off); };

    // 1. weights -> bf16 [N,K]
    wcast_t<<<dim3(96, 32), dim3(32, 8), 0, stream>>>(w_qkv,  bf(wq_off), 1024, 3072);
    wcast_t<<<dim3(32, 32), dim3(32, 8), 0, stream>>>(w_proj, bf(wp_off), 1024, 1024);
    wcast_t<<<dim3(64, 32), dim3(32, 8), 0, stream>>>(w1,     bf(w1_off), 1024, 2048);
    wcast_t<<<dim3(32, 64), dim3(32, 8), 0, stream>>>(w2,     bf(w2_off), 2048, 1024);

    // 2. h = rmsnorm(x, g1)
    rmsnorm_kernel<<<16384, 256, 0, stream>>>(x, g1, bf(h_off));

    // 3a. q = h @ Wq   [VARIANT B: 32x32x16]
    gemm256_w32<<<dim3(4, 64, 1), 512, 0, stream>>>(
        bf(h_off), bf(wq_off), bf(q_off), 1024, 1024, 1024, 1024);
    // 3b. k = h @ Wk   [VARIANT A control]
    gemm256<0><<<dim3(4, 64, 1), 512, 0, stream>>>(
        bf(h_off), bf(wq_off) + 1024 * 1024, bf(k_off), nullptr,
        1024, 1024, 1024, 1024);
    // 3c. vT = (h @ Wv)^T   [VARIANT A + scatter epilogue]
    gemm256<5><<<dim3(4, 64, 1), 512, 0, stream>>>(
        bf(h_off), bf(wq_off) + 2 * 1024 * 1024, bf(vT_off), nullptr,
        1024, 1024, 1024, 2048);

    // 4. S = q @ k^T * 1/32  (128-tile, causal block skip)
    gemm128<4, 1><<<dim3(16, 16, 8), 256, 0, stream>>>(
        bf(q_off), bf(k_off), bf(SP_off),
        1024, 1024, 1024, 2048,
        (long long)T_DIM * C_DIM, (long long)T_DIM * C_DIM, (long long)T_DIM * T_DIM,
        0.03125f);

    // 5. P = causal softmax(S), in place
    softmax_causal<<<dim3(2048, 8), 256, 0, stream>>>(bf(SP_off));

    // 6. av = P @ V  (128-tile, K clipped at diagonal)
    gemm128<0, 2><<<dim3(8, 16, 8), 256, 0, stream>>>(
        bf(SP_off), bf(vT_off), bf(k_off) /*av*/,
        2048, 2048, 2048, 1024,
        (long long)T_DIM * T_DIM, (long long)C_DIM * T_DIM, (long long)T_DIM * C_DIM,
        1.f);

    // 7. x_mid = x + av @ w_proj   (-> d_out)
    gemm256<2><<<dim3(4, 64, 1), 512, 0, stream>>>(
        bf(k_off) /*av*/, bf(wp_off), out, x,
        1024, 1024, 1024, 1024);

    // 8. h2 = rmsnorm(x_mid, g2)   (-> q region)
    rmsnorm_kernel<<<16384, 256, 0, stream>>>(out, g2, bf(q_off));

    // 9. u = silu(h2 @ w1)   (-> SP region, dead)
    gemm256<3><<<dim3(8, 64, 1), 512, 0, stream>>>(
        bf(q_off), bf(w1_off), bf(u_off), nullptr,
        1024, 1024, 1024, 2048);

    // 10. out = x_mid + u @ w2   (in place on d_out)
    gemm256<2><<<dim3(4, 64, 1), 512, 0, stream>>>(
        bf(u_off), bf(w2_off), out, (const float*)out,
        2048, 2048, 2048, 1024);
}